// Round 2
// baseline (384.340 us; speedup 1.0000x reference)
//
#include <hip/hip_runtime.h>

// Problem constants (z: [16, 64, 64, 64] f32, codebook: [2048, 64] f32)
#define BATCH   16
#define C_DIM   64
#define HGT     64
#define WID     64
#define HW      4096        // H*W
#define NROWS   65536       // B*H*W
#define N_E     2048
#define N_ELEM  4194304     // B*C*H*W
// Output layout (flat, concatenated in return order):
//   z_q_out: [16,64,64,64] = 4194304 elems | loss: 1 | perplexity: 1 | indices: 65536
#define OUT_ZQ_OFF   0
#define OUT_LOSS_OFF 4194304
#define OUT_PPL_OFF  4194305
#define OUT_IDX_OFF  4194306

// ---------------------------------------------------------------------------
// Kernel A: per-row argmax over inner products with the codebook.
// Block = 256 threads = 4 waves. Block owns 64 rows (lane = row within block).
// Wave w scans codebook quarter [w*512, w*512+512). Codebook pointer is forced
// wave-uniform (readfirstlane) so codebook reads become s_load -> SGPR
// broadcast operands of v_fmac_f32 (no LDS/VMEM bandwidth in the hot loop).
// ---------------------------------------------------------------------------
__global__ __launch_bounds__(256) void vq_argmax(
    const float* __restrict__ z, const float* __restrict__ cb,
    int* __restrict__ idx, int* __restrict__ counts)
{
    const int tid  = threadIdx.x;
    const int lane = tid & 63;
    const int wv   = __builtin_amdgcn_readfirstlane(tid >> 6);  // 0..3, uniform
    const int row0 = blockIdx.x * 64;
    const int n    = row0 + lane;
    const int b    = n >> 12;      // n / HW
    const int hw   = n & 4095;     // n % HW

    // z row into registers: z[b][c][hw], stride HW between c's.
    const float* zbase = z + ((size_t)b * C_DIM) * HW + hw;
    float zr[C_DIM];
#pragma unroll
    for (int c = 0; c < C_DIM; ++c) zr[c] = zbase[(size_t)c * HW];

    const int e0 = wv * (N_E / 4);
    const float* cbp = cb + (size_t)e0 * C_DIM;   // wave-uniform

    float best = -3.4e38f;
    int   bi   = 0;
    for (int e = 0; e < N_E / 4; e += 2) {
        const float* c0 = cbp + (size_t)e * C_DIM;
        const float* c1 = c0 + C_DIM;
        float a0 = 0.f, a1 = 0.f, a2 = 0.f, a3 = 0.f;
        float b0 = 0.f, b1 = 0.f, b2 = 0.f, b3 = 0.f;
#pragma unroll
        for (int c = 0; c < C_DIM; c += 4) {
            a0 = fmaf(zr[c + 0], c0[c + 0], a0);
            a1 = fmaf(zr[c + 1], c0[c + 1], a1);
            a2 = fmaf(zr[c + 2], c0[c + 2], a2);
            a3 = fmaf(zr[c + 3], c0[c + 3], a3);
            b0 = fmaf(zr[c + 0], c1[c + 0], b0);
            b1 = fmaf(zr[c + 1], c1[c + 1], b1);
            b2 = fmaf(zr[c + 2], c1[c + 2], b2);
            b3 = fmaf(zr[c + 3], c1[c + 3], b3);
        }
        float d0 = (a0 + a1) + (a2 + a3);
        float d1 = (b0 + b1) + (b2 + b3);
        // strict > keeps first occurrence (np.argmax semantics)
        if (d0 > best) { best = d0; bi = e0 + e; }
        if (d1 > best) { best = d1; bi = e0 + e + 1; }
    }

    // Merge the 4 waves' partial (best, idx) per row through LDS.
    __shared__ float sbest[4][64];
    __shared__ int   sbi[4][64];
    sbest[wv][lane] = best;
    sbi[wv][lane]   = bi;
    __syncthreads();
    if (tid < 64) {
        float bb = sbest[0][lane];
        int   ii = sbi[0][lane];
#pragma unroll
        for (int w = 1; w < 4; ++w) {
            float ob = sbest[w][lane];
            int   oi = sbi[w][lane];
            if (ob > bb || (ob == bb && oi < ii)) { bb = ob; ii = oi; }
        }
        idx[row0 + lane] = ii;
        atomicAdd(&counts[ii], 1);
    }
}

// ---------------------------------------------------------------------------
// Kernel B: gather z_q = codebook[idx], write straight-through output
// (zp + (z_q - zp)) back in [B,C,H,W] layout, accumulate sum((z_q-zp)^2),
// and emit indices as float32.
// ---------------------------------------------------------------------------
__global__ __launch_bounds__(256) void vq_outputs(
    const float* __restrict__ z, const float* __restrict__ cb,
    const int* __restrict__ idx, float* __restrict__ out,
    float* __restrict__ loss_accum)
{
    const int n  = blockIdx.x * 256 + threadIdx.x;
    const int b  = n >> 12;
    const int hw = n & 4095;
    const int bi = idx[n];
    out[OUT_IDX_OFF + n] = (float)bi;

    const float* zbase  = z   + ((size_t)b * C_DIM) * HW + hw;
    float*       obase  = out + ((size_t)b * C_DIM) * HW + hw;
    const float4* cbv   = (const float4*)(cb + (size_t)bi * C_DIM);

    float lsum = 0.f;
#pragma unroll
    for (int c4 = 0; c4 < C_DIM / 4; ++c4) {
        float4 qv = cbv[c4];
        float z0 = zbase[(size_t)(4 * c4 + 0) * HW];
        float z1 = zbase[(size_t)(4 * c4 + 1) * HW];
        float z2 = zbase[(size_t)(4 * c4 + 2) * HW];
        float z3 = zbase[(size_t)(4 * c4 + 3) * HW];
        float d0 = qv.x - z0, d1 = qv.y - z1, d2 = qv.z - z2, d3 = qv.w - z3;
        lsum += d0 * d0 + d1 * d1 + d2 * d2 + d3 * d3;
        obase[(size_t)(4 * c4 + 0) * HW] = z0 + d0;   // zp + (z_q - zp)
        obase[(size_t)(4 * c4 + 1) * HW] = z1 + d1;
        obase[(size_t)(4 * c4 + 2) * HW] = z2 + d2;
        obase[(size_t)(4 * c4 + 3) * HW] = z3 + d3;
    }

    // block reduction -> one atomic per block
    for (int off = 32; off > 0; off >>= 1) lsum += __shfl_down(lsum, off, 64);
    __shared__ float wsum[4];
    const int lane = threadIdx.x & 63, w = threadIdx.x >> 6;
    if (lane == 0) wsum[w] = lsum;
    __syncthreads();
    if (threadIdx.x == 0)
        atomicAdd(loss_accum, wsum[0] + wsum[1] + wsum[2] + wsum[3]);
}

// ---------------------------------------------------------------------------
// Kernel C: perplexity from histogram + loss finalize. Single block.
// ---------------------------------------------------------------------------
__global__ __launch_bounds__(256) void vq_finalize(
    const int* __restrict__ counts, const float* __restrict__ loss_accum,
    float* __restrict__ out)
{
    float h = 0.f;
    for (int e = threadIdx.x; e < N_E; e += 256) {
        float em = (float)counts[e] * (1.0f / (float)NROWS);
        h -= em * logf(em + 1e-10f);
    }
    for (int off = 32; off > 0; off >>= 1) h += __shfl_down(h, off, 64);
    __shared__ float hs[4];
    const int lane = threadIdx.x & 63, w = threadIdx.x >> 6;
    if (lane == 0) hs[w] = h;
    __syncthreads();
    if (threadIdx.x == 0) {
        float H = hs[0] + hs[1] + hs[2] + hs[3];
        float m = loss_accum[0] * (1.0f / (float)N_ELEM);
        out[OUT_LOSS_OFF] = 0.25f * m + m;   // BETA*mean + mean
        out[OUT_PPL_OFF]  = expf(H);
    }
}

extern "C" void kernel_launch(void* const* d_in, const int* in_sizes, int n_in,
                              void* d_out, int out_size, void* d_ws, size_t ws_size,
                              hipStream_t stream)
{
    const float* z  = (const float*)d_in[0];
    const float* cb = (const float*)d_in[1];
    float* out = (float*)d_out;

    // workspace layout: idx[65536] int | counts[2048] int | loss_accum float
    int*   idx        = (int*)d_ws;
    int*   counts     = (int*)((char*)d_ws + NROWS * sizeof(int));
    float* loss_accum = (float*)((char*)d_ws + NROWS * sizeof(int) + N_E * sizeof(int));

    hipMemsetAsync(counts, 0, N_E * sizeof(int) + sizeof(float), stream);

    vq_argmax<<<NROWS / 64, 256, 0, stream>>>(z, cb, idx, counts);
    vq_outputs<<<NROWS / 256, 256, 0, stream>>>(z, cb, idx, out, loss_accum);
    vq_finalize<<<1, 256, 0, stream>>>(counts, loss_accum, out);
}